// Round 3
// baseline (153.112 us; speedup 1.0000x reference)
//
#include <hip/hip_runtime.h>
#include <math.h>

#define NB 8
#define NT 4096
#define ND 1024
#define NL 3
#define NO 4
#define NLO 12
#define TWO_PI_D 6.283185307179586476925286766559
#define DT_D 0.1
#define NSTEPS 10
#define THRESH_D 0.3

// ------------- Kernel W-prep: W f32 -> f64 (96 KB, L2-resident) -------------
__global__ __launch_bounds__(256) void k_wprep(const float* __restrict__ W,
                                               double* __restrict__ wsW)
{
    int i = blockIdx.x * 256 + threadIdx.x;
    if (i < NLO * ND) wsW[i] = (double)W[i];
}

// ------------- Kernel A v3: proj (f64 dots), no LDS in main loop ------------
// Block 256 = 4 waves; block owns 64 rows; lane = row, wave = 256-d slice.
// x: per-lane 128B-line bursts from global (each line fetched once).
// W: wave-uniform offsets -> s_load (scalar pipe) feeding v_fma_f64.
__global__ __launch_bounds__(256) void k_proj(
    const float* __restrict__ x, const double* __restrict__ wsW,
    double* __restrict__ ws_ph, double* __restrict__ ws_s,
    double* __restrict__ ws_c)
{
    __shared__ double red[4 * 64 * 13];       // 26624 B
    const int tid = threadIdx.x;
    const int lane = tid & 63;
    const int wid = tid >> 6;
    const long row = (long)blockIdx.x * 64 + lane;
    const float* xr = x + row * ND + wid * 256;

    double acc[NLO];
#pragma unroll
    for (int lo = 0; lo < NLO; ++lo) acc[lo] = 0.0;

    for (int it = 0; it < 8; ++it) {          // 8 x 32 d = 256 d per wave
        float4 f[8];
#pragma unroll
        for (int q = 0; q < 8; ++q)
            f[q] = reinterpret_cast<const float4*>(xr + it * 32)[q];
        double xd[32];
#pragma unroll
        for (int q = 0; q < 8; ++q) {
            xd[q * 4 + 0] = (double)f[q].x;
            xd[q * 4 + 1] = (double)f[q].y;
            xd[q * 4 + 2] = (double)f[q].z;
            xd[q * 4 + 3] = (double)f[q].w;
        }
        const double* wp = wsW + wid * 256 + it * 32;   // wave-uniform
#pragma unroll
        for (int lo = 0; lo < NLO; ++lo) {
            const double* w = wp + lo * ND;
            double a = acc[lo];
#pragma unroll
            for (int q = 0; q < 32; ++q)
                a = fma(xd[q], w[q], a);
            acc[lo] = a;
        }
    }

    // fold 4 d-slices through LDS
#pragma unroll
    for (int lo = 0; lo < NLO; ++lo)
        red[(wid * 64 + lane) * 13 + lo] = acc[lo];
    __syncthreads();

    if (tid < 64) {
        double proj[NLO];
#pragma unroll
        for (int lo = 0; lo < NLO; ++lo)
            proj[lo] = (red[(0 * 64 + tid) * 13 + lo] +
                        red[(1 * 64 + tid) * 13 + lo]) +
                       (red[(2 * 64 + tid) * 13 + lo] +
                        red[(3 * 64 + tid) * 13 + lo]);
        const long r = (long)blockIdx.x * 64 + tid;
        const int b = (int)(r >> 12);
        const int t = (int)(r & (NT - 1));
#pragma unroll
        for (int l = 0; l < NL; ++l)
#pragma unroll
            for (int o = 0; o < NO; ++o) {
                double y = proj[l * NO + o];
                double xx = proj[l * NO + ((o + 3) & 3)] + 1e-8;
                double ph = atan2(y, xx);
                if (ph < 0.0) ph += TWO_PI_D;
                double r2 = sqrt(y * y + xx * xx);
                double s, cc;
                if (r2 > 0.0) { s = y / r2; cc = xx / r2; } else { s = 0.0; cc = 1.0; }
                long idx = ((long)((l * NB + b) * NO + o)) * NT + t;
                ws_ph[idx] = ph; ws_s[idx] = s; ws_c[idx] = cc;
            }
    }
}

// ------------- Kernel B v3: 10 Kuramoto steps, constant-angle rotation ------
#define B_THREADS 512
#define B_ELEMS (NT / B_THREADS)   // 8

__global__ __launch_bounds__(B_THREADS) void k_kuramoto(
    const float* __restrict__ omegas, const float* __restrict__ Ks,
    double* __restrict__ ws_ph, double* __restrict__ ws_s,
    double* __restrict__ ws_c, double* __restrict__ ws_r,
    float* __restrict__ out_ph)
{
    const int g = blockIdx.x;              // (l*NB + b)*NO + o
    const int l = g >> 5;
    const int b = (g >> 2) & 7;
    const int o = g & 3;
    const double om = (double)omegas[l * NO + o];
    const double Kv = (double)Ks[l];
    const double dtom = DT_D * om;         // constant step angle (coupling aside)
    const double cKT = DT_D * Kv / (double)NT;  // |eps| <= dt*K/T ~ 5e-5
    double sA, cA; sincos(dtom, &sA, &cA);
    const int tid = threadIdx.x;
    const int wid = tid >> 6;
    const int lane = tid & 63;
    __shared__ double lds[18];

    double ph[B_ELEMS], s[B_ELEMS], c[B_ELEMS];
#pragma unroll
    for (int k = 0; k < B_ELEMS; ++k) {
        long idx = (long)g * NT + tid + k * B_THREADS;
        ph[k] = ws_ph[idx]; s[k] = ws_s[idx]; c[k] = ws_c[idx];
    }

    for (int step = 0; step < NSTEPS; ++step) {
        double ts = 0.0, tc = 0.0;
#pragma unroll
        for (int k = 0; k < B_ELEMS; ++k) { ts += s[k]; tc += c[k]; }
#pragma unroll
        for (int off = 32; off > 0; off >>= 1) {
            ts += __shfl_down(ts, off);
            tc += __shfl_down(tc, off);
        }
        if (lane == 0) { lds[wid] = ts; lds[8 + wid] = tc; }
        __syncthreads();
        if (tid == 0) {
            double S = 0.0, C = 0.0;
#pragma unroll
            for (int w = 0; w < 8; ++w) { S += lds[w]; C += lds[8 + w]; }
            // sin/cos of atan2(S/T, C/T) via normalization (exact identity)
            double r2 = sqrt(S * S + C * C);
            double sm, cm;
            if (r2 > 0.0) { sm = S / r2; cm = C / r2; } else { sm = 0.0; cm = 1.0; }
            lds[16] = sm; lds[17] = cm;
        }
        __syncthreads();
        const double sm = lds[16], cm = lds[17];
#pragma unroll
        for (int k = 0; k < B_ELEMS; ++k) {
            double sv = sm * c[k] - cm * s[k];      // sin(mean - ph)
            double eps = cKT * sv;                  // |eps| <= ~5e-5
            double val = ph[k] + (dtom + eps);
            if (val >= TWO_PI_D) val -= TWO_PI_D;   // exact (Sterbenz)
            if (val < 0.0) val += TWO_PI_D;
            ph[k] = val;
            // rotate (s,c) by dtom+eps: sd = sA + cA*eps, cd = cA - sA*eps
            double sd = fma(cA, eps, sA);
            double cd = fma(-sA, eps, cA);
            double sn = fma(s[k], cd, c[k] * sd);
            double cn = fma(c[k], cd, -(s[k] * sd));
            s[k] = sn; c[k] = cn;
        }
        __syncthreads();               // protect lds before next step's writes
    }
    // level coherence from final s,c
    {
        double ts = 0.0, tc = 0.0;
#pragma unroll
        for (int k = 0; k < B_ELEMS; ++k) { ts += s[k]; tc += c[k]; }
#pragma unroll
        for (int off = 32; off > 0; off >>= 1) {
            ts += __shfl_down(ts, off);
            tc += __shfl_down(tc, off);
        }
        if (lane == 0) { lds[wid] = ts; lds[8 + wid] = tc; }
        __syncthreads();
        if (tid == 0) {
            double S = 0.0, C = 0.0;
#pragma unroll
            for (int w = 0; w < 8; ++w) { S += lds[w]; C += lds[8 + w]; }
            double Sm = S / (double)NT, Cm = C / (double)NT;
            ws_r[g] = sqrt(Sm * Sm + Cm * Cm);
        }
    }
#pragma unroll
    for (int k = 0; k < B_ELEMS; ++k) {
        int t = tid + k * B_THREADS;
        long idx = (long)g * NT + t;
        ws_s[idx] = s[k]; ws_c[idx] = c[k];                             // final s,c for k_mask
        out_ph[((long)(l * NB + b) * NT + t) * NO + o] = (float)ph[k];  // (L,B,T,O)
    }
}

// ------------- Kernel C: windowed coherence -> boundary mask (no sincos) ----
__global__ __launch_bounds__(256) void k_mask(
    const double* __restrict__ ws_s, const double* __restrict__ ws_c,
    float* __restrict__ out_mask)
{
    const int bid = blockIdx.x;            // 24 lb * 16 t-slices
    const int lb = bid >> 4;               // l*NB + b
    const int t0 = ((bid & 15) << 8) + threadIdx.x;
    float* mrow = out_mask + (long)lb * (NT - 2);
    if ((bid & 15) == 0 && threadIdx.x < 2) mrow[threadIdx.x] = 0.0f;
    if (t0 >= NT - 4) return;
    double q[3] = {0.0, 0.0, 0.0};
#pragma unroll
    for (int o = 0; o < NO; ++o) {
        const double* ps = ws_s + ((long)lb * NO + o) * NT + t0;
        const double* pc = ws_c + ((long)lb * NO + o) * NT + t0;
        double sv[5], cv[5];
#pragma unroll
        for (int j = 0; j < 5; ++j) { sv[j] = ps[j]; cv[j] = pc[j]; }
#pragma unroll
        for (int j = 0; j < 3; ++j) {
            double ms = ((sv[j] + sv[j + 1]) + sv[j + 2]) / 3.0;
            double mc = ((cv[j] + cv[j + 1]) + cv[j + 2]) / 3.0;
            q[j] += sqrt(ms * ms + mc * mc);
        }
    }
    double coh0 = q[0] / 4.0, coh1 = q[1] / 4.0, coh2 = q[2] / 4.0;
    bool cond = (coh1 < coh0 - THRESH_D) && (coh1 < coh2 - THRESH_D);
    mrow[2 + t0] = cond ? 1.0f : 0.0f;
}

// ------------- Kernel D: level coherences (24 values) -----------------------
__global__ void k_level(const double* __restrict__ ws_r, float* __restrict__ out_lvl)
{
    const int tid = threadIdx.x;
    if (tid < NB * NL) {
        const int b = tid / NL, l = tid % NL;   // output is (B, L)
        const double* r = ws_r + (long)(l * NB + b) * NO;
        double m = (((r[0] + r[1]) + r[2]) + r[3]) / 4.0;
        out_lvl[tid] = (float)m;
    }
}

extern "C" void kernel_launch(void* const* d_in, const int* in_sizes, int n_in,
                              void* d_out, int out_size, void* d_ws, size_t ws_size,
                              hipStream_t stream)
{
    const float* x      = (const float*)d_in[0];
    const float* W      = (const float*)d_in[1];
    const float* omegas = (const float*)d_in[2];
    const float* Ks     = (const float*)d_in[3];
    float* out = (float*)d_out;

    double* wsW   = (double*)d_ws;                 // 12288 f64
    double* ws_ph = wsW + NLO * ND;                // 393216 f64
    double* ws_s  = ws_ph + (long)NLO * NB * NT;   // 393216 f64
    double* ws_c  = ws_s + (long)NLO * NB * NT;    // 393216 f64
    double* ws_r  = ws_c + (long)NLO * NB * NT;    // 96 f64

    float* out_ph   = out;            // 393216
    float* out_lvl  = out + 393216;   // 24
    float* out_mask = out + 393240;   // 98256

    k_wprep<<<(NLO * ND + 255) / 256, 256, 0, stream>>>(W, wsW);
    k_proj<<<NB * NT / 64, 256, 0, stream>>>(x, wsW, ws_ph, ws_s, ws_c);
    k_kuramoto<<<NL * NB * NO, B_THREADS, 0, stream>>>(omegas, Ks, ws_ph, ws_s, ws_c, ws_r, out_ph);
    k_mask<<<24 * 16, 256, 0, stream>>>(ws_s, ws_c, out_mask);
    k_level<<<1, 64, 0, stream>>>(ws_r, out_lvl);
}

// Round 4
// 88.797 us; speedup vs baseline: 1.7243x; 1.7243x over previous
//
#include <hip/hip_runtime.h>
#include <math.h>

#define NB 8
#define NT 4096
#define ND 1024
#define NL 3
#define NO 4
#define NLO 12
#define TWO_PI_D 6.283185307179586476925286766559
#define DT_D 0.1
#define NSTEPS 10
#define THRESH_D 0.3

// ------------- Kernel W-prep: W f32 -> f64 (96 KB, L2-resident) -------------
__global__ __launch_bounds__(256) void k_wprep(const float* __restrict__ W,
                                               double* __restrict__ wsW)
{
    int i = blockIdx.x * 256 + threadIdx.x;
    if (i < NLO * ND) wsW[i] = (double)W[i];
}

// ------------- Kernel A v4: proj via SGPR-broadcast W -----------------------
// Block 256 = 4 waves; block owns 64 rows; lane = row, wave = 256-d slice.
// W base made provably wave-uniform via readfirstlane -> compiler emits
// s_load into SGPRs; v_fma_f64 takes the SGPR pair as the one scalar operand.
// No LDS in the main loop; x read as 128B/lane bursts from global.
__global__ __launch_bounds__(256) void k_proj(
    const float* __restrict__ x, const double* __restrict__ wsW,
    double* __restrict__ ws_ph, double* __restrict__ ws_s,
    double* __restrict__ ws_c)
{
    __shared__ double red[4 * 64 * 13];       // 26624 B
    const int tid = threadIdx.x;
    const int lane = tid & 63;
    const int wid = __builtin_amdgcn_readfirstlane(tid >> 6);   // uniform!
    const long row = (long)blockIdx.x * 64 + lane;
    const float* xr = x + row * ND + wid * 256;
    const double* wbase = wsW + wid * 256;    // uniform base -> s_load path

    double acc[NLO];
#pragma unroll
    for (int lo = 0; lo < NLO; ++lo) acc[lo] = 0.0;

    for (int it = 0; it < 8; ++it) {          // 8 x 32 d = 256 d per wave
        float4 f[8];
#pragma unroll
        for (int q = 0; q < 8; ++q)
            f[q] = reinterpret_cast<const float4*>(xr + it * 32)[q];
        double xd[32];
#pragma unroll
        for (int q = 0; q < 8; ++q) {
            xd[q * 4 + 0] = (double)f[q].x;
            xd[q * 4 + 1] = (double)f[q].y;
            xd[q * 4 + 2] = (double)f[q].z;
            xd[q * 4 + 3] = (double)f[q].w;
        }
        const double* wp = wbase + it * 32;   // uniform
#pragma unroll
        for (int dd = 0; dd < 32; dd += 4) {
#pragma unroll
            for (int lo = 0; lo < NLO; ++lo) {
                double a = acc[lo];
                a = fma(xd[dd + 0], wp[lo * ND + dd + 0], a);
                a = fma(xd[dd + 1], wp[lo * ND + dd + 1], a);
                a = fma(xd[dd + 2], wp[lo * ND + dd + 2], a);
                a = fma(xd[dd + 3], wp[lo * ND + dd + 3], a);
                acc[lo] = a;
            }
        }
    }

    // fold 4 d-slices through LDS
#pragma unroll
    for (int lo = 0; lo < NLO; ++lo)
        red[(wid * 64 + lane) * 13 + lo] = acc[lo];
    __syncthreads();

    if (tid < 192) {                          // thread = (l = tid>>6, row = tid&63)
        const int l = tid >> 6;
        const int rs = tid & 63;
        double proj[NO];
#pragma unroll
        for (int o = 0; o < NO; ++o) {
            int lo = l * NO + o;
            proj[o] = (red[(0 * 64 + rs) * 13 + lo] +
                       red[(1 * 64 + rs) * 13 + lo]) +
                      (red[(2 * 64 + rs) * 13 + lo] +
                       red[(3 * 64 + rs) * 13 + lo]);
        }
        const long r = (long)blockIdx.x * 64 + rs;
        const int b = (int)(r >> 12);
        const int t = (int)(r & (NT - 1));
#pragma unroll
        for (int o = 0; o < NO; ++o) {
            double y = proj[o];
            double xx = proj[(o + 3) & 3] + 1e-8;
            double ph = atan2(y, xx);
            if (ph < 0.0) ph += TWO_PI_D;
            double r2 = sqrt(y * y + xx * xx);
            double s, cc;
            if (r2 > 0.0) { s = y / r2; cc = xx / r2; } else { s = 0.0; cc = 1.0; }
            long idx = ((long)((l * NB + b) * NO + o)) * NT + t;
            ws_ph[idx] = ph; ws_s[idx] = s; ws_c[idx] = cc;
        }
    }
}

// ------------- Kernel B v3: 10 Kuramoto steps, constant-angle rotation ------
#define B_THREADS 512
#define B_ELEMS (NT / B_THREADS)   // 8

__global__ __launch_bounds__(B_THREADS) void k_kuramoto(
    const float* __restrict__ omegas, const float* __restrict__ Ks,
    double* __restrict__ ws_ph, double* __restrict__ ws_s,
    double* __restrict__ ws_c, double* __restrict__ ws_r,
    float* __restrict__ out_ph)
{
    const int g = blockIdx.x;              // (l*NB + b)*NO + o
    const int l = g >> 5;
    const int b = (g >> 2) & 7;
    const int o = g & 3;
    const double om = (double)omegas[l * NO + o];
    const double Kv = (double)Ks[l];
    const double dtom = DT_D * om;         // constant step angle (coupling aside)
    const double cKT = DT_D * Kv / (double)NT;  // |eps| <= dt*K/T ~ 5e-5
    double sA, cA; sincos(dtom, &sA, &cA);
    const int tid = threadIdx.x;
    const int wid = tid >> 6;
    const int lane = tid & 63;
    __shared__ double lds[18];

    double ph[B_ELEMS], s[B_ELEMS], c[B_ELEMS];
#pragma unroll
    for (int k = 0; k < B_ELEMS; ++k) {
        long idx = (long)g * NT + tid + k * B_THREADS;
        ph[k] = ws_ph[idx]; s[k] = ws_s[idx]; c[k] = ws_c[idx];
    }

    for (int step = 0; step < NSTEPS; ++step) {
        double ts = 0.0, tc = 0.0;
#pragma unroll
        for (int k = 0; k < B_ELEMS; ++k) { ts += s[k]; tc += c[k]; }
#pragma unroll
        for (int off = 32; off > 0; off >>= 1) {
            ts += __shfl_down(ts, off);
            tc += __shfl_down(tc, off);
        }
        if (lane == 0) { lds[wid] = ts; lds[8 + wid] = tc; }
        __syncthreads();
        if (tid == 0) {
            double S = 0.0, C = 0.0;
#pragma unroll
            for (int w = 0; w < 8; ++w) { S += lds[w]; C += lds[8 + w]; }
            // sin/cos of atan2(S/T, C/T) via normalization (exact identity)
            double r2 = sqrt(S * S + C * C);
            double sm, cm;
            if (r2 > 0.0) { sm = S / r2; cm = C / r2; } else { sm = 0.0; cm = 1.0; }
            lds[16] = sm; lds[17] = cm;
        }
        __syncthreads();
        const double sm = lds[16], cm = lds[17];
#pragma unroll
        for (int k = 0; k < B_ELEMS; ++k) {
            double sv = sm * c[k] - cm * s[k];      // sin(mean - ph)
            double eps = cKT * sv;                  // |eps| <= ~5e-5
            double val = ph[k] + (dtom + eps);
            if (val >= TWO_PI_D) val -= TWO_PI_D;   // exact (Sterbenz)
            if (val < 0.0) val += TWO_PI_D;
            ph[k] = val;
            // rotate (s,c) by dtom+eps: sd = sA + cA*eps, cd = cA - sA*eps
            double sd = fma(cA, eps, sA);
            double cd = fma(-sA, eps, cA);
            double sn = fma(s[k], cd, c[k] * sd);
            double cn = fma(c[k], cd, -(s[k] * sd));
            s[k] = sn; c[k] = cn;
        }
        __syncthreads();               // protect lds before next step's writes
    }
    // level coherence from final s,c
    {
        double ts = 0.0, tc = 0.0;
#pragma unroll
        for (int k = 0; k < B_ELEMS; ++k) { ts += s[k]; tc += c[k]; }
#pragma unroll
        for (int off = 32; off > 0; off >>= 1) {
            ts += __shfl_down(ts, off);
            tc += __shfl_down(tc, off);
        }
        if (lane == 0) { lds[wid] = ts; lds[8 + wid] = tc; }
        __syncthreads();
        if (tid == 0) {
            double S = 0.0, C = 0.0;
#pragma unroll
            for (int w = 0; w < 8; ++w) { S += lds[w]; C += lds[8 + w]; }
            double Sm = S / (double)NT, Cm = C / (double)NT;
            ws_r[g] = sqrt(Sm * Sm + Cm * Cm);
        }
    }
#pragma unroll
    for (int k = 0; k < B_ELEMS; ++k) {
        int t = tid + k * B_THREADS;
        long idx = (long)g * NT + t;
        ws_s[idx] = s[k]; ws_c[idx] = c[k];                             // final s,c for k_mask
        out_ph[((long)(l * NB + b) * NT + t) * NO + o] = (float)ph[k];  // (L,B,T,O)
    }
}

// ------------- Kernel C: windowed coherence -> boundary mask (no sincos) ----
__global__ __launch_bounds__(256) void k_mask(
    const double* __restrict__ ws_s, const double* __restrict__ ws_c,
    float* __restrict__ out_mask)
{
    const int bid = blockIdx.x;            // 24 lb * 16 t-slices
    const int lb = bid >> 4;               // l*NB + b
    const int t0 = ((bid & 15) << 8) + threadIdx.x;
    float* mrow = out_mask + (long)lb * (NT - 2);
    if ((bid & 15) == 0 && threadIdx.x < 2) mrow[threadIdx.x] = 0.0f;
    if (t0 >= NT - 4) return;
    double q[3] = {0.0, 0.0, 0.0};
#pragma unroll
    for (int o = 0; o < NO; ++o) {
        const double* ps = ws_s + ((long)lb * NO + o) * NT + t0;
        const double* pc = ws_c + ((long)lb * NO + o) * NT + t0;
        double sv[5], cv[5];
#pragma unroll
        for (int j = 0; j < 5; ++j) { sv[j] = ps[j]; cv[j] = pc[j]; }
#pragma unroll
        for (int j = 0; j < 3; ++j) {
            double ms = ((sv[j] + sv[j + 1]) + sv[j + 2]) / 3.0;
            double mc = ((cv[j] + cv[j + 1]) + cv[j + 2]) / 3.0;
            q[j] += sqrt(ms * ms + mc * mc);
        }
    }
    double coh0 = q[0] / 4.0, coh1 = q[1] / 4.0, coh2 = q[2] / 4.0;
    bool cond = (coh1 < coh0 - THRESH_D) && (coh1 < coh2 - THRESH_D);
    mrow[2 + t0] = cond ? 1.0f : 0.0f;
}

// ------------- Kernel D: level coherences (24 values) -----------------------
__global__ void k_level(const double* __restrict__ ws_r, float* __restrict__ out_lvl)
{
    const int tid = threadIdx.x;
    if (tid < NB * NL) {
        const int b = tid / NL, l = tid % NL;   // output is (B, L)
        const double* r = ws_r + (long)(l * NB + b) * NO;
        double m = (((r[0] + r[1]) + r[2]) + r[3]) / 4.0;
        out_lvl[tid] = (float)m;
    }
}

extern "C" void kernel_launch(void* const* d_in, const int* in_sizes, int n_in,
                              void* d_out, int out_size, void* d_ws, size_t ws_size,
                              hipStream_t stream)
{
    const float* x      = (const float*)d_in[0];
    const float* W      = (const float*)d_in[1];
    const float* omegas = (const float*)d_in[2];
    const float* Ks     = (const float*)d_in[3];
    float* out = (float*)d_out;

    double* wsW   = (double*)d_ws;                 // 12288 f64
    double* ws_ph = wsW + NLO * ND;                // 393216 f64
    double* ws_s  = ws_ph + (long)NLO * NB * NT;   // 393216 f64
    double* ws_c  = ws_s + (long)NLO * NB * NT;    // 393216 f64
    double* ws_r  = ws_c + (long)NLO * NB * NT;    // 96 f64

    float* out_ph   = out;            // 393216
    float* out_lvl  = out + 393216;   // 24
    float* out_mask = out + 393240;   // 98256

    k_wprep<<<(NLO * ND + 255) / 256, 256, 0, stream>>>(W, wsW);
    k_proj<<<NB * NT / 64, 256, 0, stream>>>(x, wsW, ws_ph, ws_s, ws_c);
    k_kuramoto<<<NL * NB * NO, B_THREADS, 0, stream>>>(omegas, Ks, ws_ph, ws_s, ws_c, ws_r, out_ph);
    k_mask<<<24 * 16, 256, 0, stream>>>(ws_s, ws_c, out_mask);
    k_level<<<1, 64, 0, stream>>>(ws_r, out_lvl);
}

// Round 5
// 69.842 us; speedup vs baseline: 2.1923x; 1.2714x over previous
//
#include <hip/hip_runtime.h>
#include <math.h>

#define NB 8
#define NT 4096
#define ND 1024
#define NL 3
#define NO 4
#define NLO 12
#define TWO_PI_D 6.283185307179586476925286766559
#define DT_D 0.1
#define NSTEPS 10
#define THRESH_D 0.3

// ------------- Kernel W-prep: W f32 -> f64 (96 KB, L2-resident) -------------
__global__ __launch_bounds__(256) void k_wprep(const float* __restrict__ W,
                                               double* __restrict__ wsW)
{
    int i = blockIdx.x * 256 + threadIdx.x;
    if (i < NLO * ND) wsW[i] = (double)W[i];
}

// ------------- Kernel A v6: proj; LDS-staged x + SGPR-broadcast W -----------
// Block 512 thr = 8 waves; block owns 64 rows; wave w owns d-slice [128w,128w+128).
// Per 32-d it: wave stages [64 rows x 32 d] f32 into its own 8 KB LDS tile
// (coalesced: 8 lanes = one 128B line), XOR-swizzled 16B slots (conflict-free
// b128 reads), wave-synchronous (no barrier). W via readfirstlane-uniform
// s_load feeding v_fma_f64. 4 waves/SIMD hide s_load + vmcnt latency.
__global__ __launch_bounds__(512, 4) void k_proj(
    const float* __restrict__ x, const double* __restrict__ wsW,
    double* __restrict__ ws_ph, float* __restrict__ ws_s,
    float* __restrict__ ws_c)
{
    __shared__ char buf[65536];               // 8 waves x 8 KB tiles; red overlay
    const int tid = threadIdx.x;
    const int lane = tid & 63;
    const int wid = __builtin_amdgcn_readfirstlane(tid >> 6);   // 0..7, uniform
    const long row0 = (long)blockIdx.x * 64;
    const double* wbase = wsW + wid * 128;    // uniform base -> s_load path
    float* tile = reinterpret_cast<float*>(buf) + wid * 2048;   // 8 KB per wave

    double acc[NLO];
#pragma unroll
    for (int lo = 0; lo < NLO; ++lo) acc[lo] = 0.0;

    const int rg = lane >> 3;                 // global-stage row group
    const int slot = lane & 7;                // 16B slot within 32-d window

    for (int it = 0; it < 4; ++it) {          // 4 x 32 d = 128 d per wave
        // stage [64 rows x 32 d]: 8 lanes cover one row's 128B window = 1 line
#pragma unroll
        for (int p = 0; p < 8; ++p) {
            int r = p * 8 + rg;
            float4 v = *reinterpret_cast<const float4*>(
                x + (row0 + r) * ND + wid * 128 + it * 32 + slot * 4);
            *reinterpret_cast<float4*>(
                &tile[r * 32 + ((slot ^ (r & 7)) * 4)]) = v;
        }
        // wave-synchronous: compiler inserts vmcnt/lgkmcnt before dependent reads
        float4 f[8];
#pragma unroll
        for (int q = 0; q < 8; ++q)
            f[q] = *reinterpret_cast<const float4*>(
                &tile[lane * 32 + ((q ^ (lane & 7)) * 4)]);

        const double* wp = wbase + it * 32;   // uniform
#pragma unroll
        for (int q = 0; q < 8; ++q) {
            double x0 = (double)f[q].x, x1 = (double)f[q].y;
            double x2 = (double)f[q].z, x3 = (double)f[q].w;
#pragma unroll
            for (int lo = 0; lo < NLO; ++lo) {
                double a = acc[lo];
                a = fma(x0, wp[lo * ND + q * 4 + 0], a);
                a = fma(x1, wp[lo * ND + q * 4 + 1], a);
                a = fma(x2, wp[lo * ND + q * 4 + 2], a);
                a = fma(x3, wp[lo * ND + q * 4 + 3], a);
                acc[lo] = a;
            }
        }
    }

    // fold 8 d-slices: red overlays the tile space (all waves done with tiles)
    __syncthreads();
    double* red = reinterpret_cast<double*>(buf);
#pragma unroll
    for (int lo = 0; lo < NLO; ++lo)
        red[(wid * 64 + lane) * 13 + lo] = acc[lo];
    __syncthreads();

    if (tid < 192) {                          // thread = (l = tid>>6, row = tid&63)
        const int l = tid >> 6;
        const int rs = tid & 63;
        double proj[NO];
#pragma unroll
        for (int o = 0; o < NO; ++o) {
            int lo = l * NO + o;
            double p0 = 0.0;
#pragma unroll
            for (int w = 0; w < 8; ++w)
                p0 += red[(w * 64 + rs) * 13 + lo];
            proj[o] = p0;
        }
        const long r = row0 + rs;
        const int b = (int)(r >> 12);
        const int t = (int)(r & (NT - 1));
#pragma unroll
        for (int o = 0; o < NO; ++o) {
            double y = proj[o];
            double xx = proj[(o + 3) & 3] + 1e-8;
            double ph = atan2(y, xx);
            if (ph < 0.0) ph += TWO_PI_D;
            double r2 = sqrt(y * y + xx * xx);
            double s, cc;
            if (r2 > 0.0) { s = y / r2; cc = xx / r2; } else { s = 0.0; cc = 1.0; }
            long idx = ((long)((l * NB + b) * NO + o)) * NT + t;
            ws_ph[idx] = ph; ws_s[idx] = (float)s; ws_c[idx] = (float)cc;
        }
    }
}

// ------------- Kernel B: 10 Kuramoto steps, constant-angle rotation ---------
#define B_THREADS 512
#define B_ELEMS (NT / B_THREADS)   // 8

__global__ __launch_bounds__(B_THREADS) void k_kuramoto(
    const float* __restrict__ omegas, const float* __restrict__ Ks,
    double* __restrict__ ws_ph, float* __restrict__ ws_s,
    float* __restrict__ ws_c, double* __restrict__ ws_r,
    float* __restrict__ out_ph)
{
    const int g = blockIdx.x;              // (l*NB + b)*NO + o
    const int l = g >> 5;
    const int b = (g >> 2) & 7;
    const int o = g & 3;
    const double om = (double)omegas[l * NO + o];
    const double Kv = (double)Ks[l];
    const double dtom = DT_D * om;
    const double cKT = DT_D * Kv / (double)NT;  // |eps| <= dt*K/T ~ 5e-5
    double sA, cA; sincos(dtom, &sA, &cA);
    const int tid = threadIdx.x;
    const int wid = tid >> 6;
    const int lane = tid & 63;
    __shared__ double lds[18];

    double ph[B_ELEMS], s[B_ELEMS], c[B_ELEMS];
#pragma unroll
    for (int k = 0; k < B_ELEMS; ++k) {
        long idx = (long)g * NT + tid + k * B_THREADS;
        ph[k] = ws_ph[idx]; s[k] = (double)ws_s[idx]; c[k] = (double)ws_c[idx];
    }

    for (int step = 0; step < NSTEPS; ++step) {
        double ts = 0.0, tc = 0.0;
#pragma unroll
        for (int k = 0; k < B_ELEMS; ++k) { ts += s[k]; tc += c[k]; }
#pragma unroll
        for (int off = 32; off > 0; off >>= 1) {
            ts += __shfl_down(ts, off);
            tc += __shfl_down(tc, off);
        }
        if (lane == 0) { lds[wid] = ts; lds[8 + wid] = tc; }
        __syncthreads();
        if (tid == 0) {
            double S = 0.0, C = 0.0;
#pragma unroll
            for (int w = 0; w < 8; ++w) { S += lds[w]; C += lds[8 + w]; }
            double r2 = sqrt(S * S + C * C);
            double sm, cm;
            if (r2 > 0.0) { sm = S / r2; cm = C / r2; } else { sm = 0.0; cm = 1.0; }
            lds[16] = sm; lds[17] = cm;
        }
        __syncthreads();
        const double sm = lds[16], cm = lds[17];
#pragma unroll
        for (int k = 0; k < B_ELEMS; ++k) {
            double sv = sm * c[k] - cm * s[k];      // sin(mean - ph)
            double eps = cKT * sv;                  // |eps| <= ~5e-5
            double val = ph[k] + (dtom + eps);
            if (val >= TWO_PI_D) val -= TWO_PI_D;   // exact (Sterbenz)
            if (val < 0.0) val += TWO_PI_D;
            ph[k] = val;
            // rotate (s,c) by dtom+eps: sd = sA + cA*eps, cd = cA - sA*eps
            double sd = fma(cA, eps, sA);
            double cd = fma(-sA, eps, cA);
            double sn = fma(s[k], cd, c[k] * sd);
            double cn = fma(c[k], cd, -(s[k] * sd));
            s[k] = sn; c[k] = cn;
        }
        __syncthreads();               // protect lds before next step's writes
    }
    // level coherence from final s,c
    {
        double ts = 0.0, tc = 0.0;
#pragma unroll
        for (int k = 0; k < B_ELEMS; ++k) { ts += s[k]; tc += c[k]; }
#pragma unroll
        for (int off = 32; off > 0; off >>= 1) {
            ts += __shfl_down(ts, off);
            tc += __shfl_down(tc, off);
        }
        if (lane == 0) { lds[wid] = ts; lds[8 + wid] = tc; }
        __syncthreads();
        if (tid == 0) {
            double S = 0.0, C = 0.0;
#pragma unroll
            for (int w = 0; w < 8; ++w) { S += lds[w]; C += lds[8 + w]; }
            double Sm = S / (double)NT, Cm = C / (double)NT;
            ws_r[g] = sqrt(Sm * Sm + Cm * Cm);
        }
    }
#pragma unroll
    for (int k = 0; k < B_ELEMS; ++k) {
        int t = tid + k * B_THREADS;
        long idx = (long)g * NT + t;
        ws_s[idx] = (float)s[k]; ws_c[idx] = (float)c[k];               // final s,c for k_mask
        out_ph[((long)(l * NB + b) * NT + t) * NO + o] = (float)ph[k];  // (L,B,T,O)
    }
}

// ------------- Kernel C: windowed coherence -> boundary mask ----------------
__global__ __launch_bounds__(256) void k_mask(
    const float* __restrict__ ws_s, const float* __restrict__ ws_c,
    float* __restrict__ out_mask)
{
    const int bid = blockIdx.x;            // 24 lb * 16 t-slices
    const int lb = bid >> 4;               // l*NB + b
    const int t0 = ((bid & 15) << 8) + threadIdx.x;
    float* mrow = out_mask + (long)lb * (NT - 2);
    if ((bid & 15) == 0 && threadIdx.x < 2) mrow[threadIdx.x] = 0.0f;
    if (t0 >= NT - 4) return;
    double q[3] = {0.0, 0.0, 0.0};
#pragma unroll
    for (int o = 0; o < NO; ++o) {
        const float* ps = ws_s + ((long)lb * NO + o) * NT + t0;
        const float* pc = ws_c + ((long)lb * NO + o) * NT + t0;
        double sv[5], cv[5];
#pragma unroll
        for (int j = 0; j < 5; ++j) { sv[j] = (double)ps[j]; cv[j] = (double)pc[j]; }
#pragma unroll
        for (int j = 0; j < 3; ++j) {
            double ms = ((sv[j] + sv[j + 1]) + sv[j + 2]) / 3.0;
            double mc = ((cv[j] + cv[j + 1]) + cv[j + 2]) / 3.0;
            q[j] += sqrt(ms * ms + mc * mc);
        }
    }
    double coh0 = q[0] / 4.0, coh1 = q[1] / 4.0, coh2 = q[2] / 4.0;
    bool cond = (coh1 < coh0 - THRESH_D) && (coh1 < coh2 - THRESH_D);
    mrow[2 + t0] = cond ? 1.0f : 0.0f;
}

// ------------- Kernel D: level coherences (24 values) -----------------------
__global__ void k_level(const double* __restrict__ ws_r, float* __restrict__ out_lvl)
{
    const int tid = threadIdx.x;
    if (tid < NB * NL) {
        const int b = tid / NL, l = tid % NL;   // output is (B, L)
        const double* r = ws_r + (long)(l * NB + b) * NO;
        double m = (((r[0] + r[1]) + r[2]) + r[3]) / 4.0;
        out_lvl[tid] = (float)m;
    }
}

extern "C" void kernel_launch(void* const* d_in, const int* in_sizes, int n_in,
                              void* d_out, int out_size, void* d_ws, size_t ws_size,
                              hipStream_t stream)
{
    const float* x      = (const float*)d_in[0];
    const float* W      = (const float*)d_in[1];
    const float* omegas = (const float*)d_in[2];
    const float* Ks     = (const float*)d_in[3];
    float* out = (float*)d_out;

    double* wsW   = (double*)d_ws;                  // 12288 f64
    double* ws_ph = wsW + NLO * ND;                 // 393216 f64
    float*  ws_s  = (float*)(ws_ph + (long)NLO * NB * NT);   // 393216 f32
    float*  ws_c  = ws_s + (long)NLO * NB * NT;              // 393216 f32
    double* ws_r  = (double*)(ws_c + (long)NLO * NB * NT);   // 96 f64

    float* out_ph   = out;            // 393216
    float* out_lvl  = out + 393216;   // 24
    float* out_mask = out + 393240;   // 98256

    k_wprep<<<(NLO * ND + 255) / 256, 256, 0, stream>>>(W, wsW);
    k_proj<<<NB * NT / 64, 512, 0, stream>>>(x, wsW, ws_ph, ws_s, ws_c);
    k_kuramoto<<<NL * NB * NO, B_THREADS, 0, stream>>>(omegas, Ks, ws_ph, ws_s, ws_c, ws_r, out_ph);
    k_mask<<<24 * 16, 256, 0, stream>>>(ws_s, ws_c, out_mask);
    k_level<<<1, 64, 0, stream>>>(ws_r, out_lvl);
}